// Round 1
// baseline (536.546 us; speedup 1.0000x reference)
//
#include <hip/hip_runtime.h>
#include <math.h>

#define NN 16384
#define KK 16
#define LIST 17   // K+1, self included

__device__ __forceinline__ bool lexless(float da, int ia, float db, int ib) {
    return (da < db) || ((da == db) && (ia < ib));
}

// One wave (64 lanes) per row. Top-17 kept distributed across lanes 0..16,
// sorted ascending by (dist, idx). Lanes 17..63 hold +INF sentinels.
__global__ void knn_adj_kernel(const float* __restrict__ nodes,
                               float* __restrict__ out) {
#pragma clang fp contract(off)
    const int lane = threadIdx.x & 63;
    const int wave = threadIdx.x >> 6;
    const int row  = blockIdx.x * 4 + wave;

    // Own coordinates (wave-uniform loads, cached).
    const float xi = nodes[3 * row + 0];
    const float yi = nodes[3 * row + 1];
    const float zi = nodes[3 * row + 2];
    // Reference: sq = sum(nodes*nodes, axis=1) -> ((x*x + y*y) + z*z), no fma.
    const float sqi = (xi * xi + yi * yi) + zi * zi;

    float ld = INFINITY;        // my list entry (valid on lanes 0..16)
    int   li = 0x7fffffff;
    float td = INFINITY;        // current worst (lane 16's entry), broadcast
    int   ti = 0x7fffffff;
    float td2u = INFINITY;      // conservative d2 screen: d2 > td2u => cannot pass

    for (int t = 0; t < NN / 64; ++t) {
        const int j = t * 64 + lane;
        const float xj = nodes[3 * j + 0];
        const float yj = nodes[3 * j + 1];
        const float zj = nodes[3 * j + 2];
        const float sqj = (xj * xj + yj * yj) + zj * zj;
        // Reference matmul: fma chain with init 0 -> fma(z, z', fma(y, y', x*x')).
        const float dot = fmaf(zi, zj, fmaf(yi, yj, xi * xj));
        const float d2  = (sqi + sqj) - 2.0f * dot;

        const bool rough = (d2 <= td2u);
        if (__any(rough)) {
            float dist = INFINITY;
            if (rough) dist = sqrtf(fmaxf(d2, 0.0f));   // IEEE sqrt, matches ref
            bool done = false;
            while (true) {
                // Re-screen every round: threshold tightens as we insert.
                const bool pass = (!done) && rough && lexless(dist, j, td, ti);
                const unsigned long long m = __ballot(pass);
                if (m == 0ull) break;
                const int src = __ffsll(m) - 1;
                const float dc = __shfl(dist, src);
                const int   ic = __shfl(j,    src);
                if (lane == src) done = true;
                // Insert (dc,ic) into the distributed sorted list.
                const bool gt = lexless(dc, ic, ld, li);   // true on a suffix of lanes
                const unsigned long long gm = __ballot(gt);
                const int p = __ffsll(gm) - 1;             // insertion position
                const float pd = __shfl_up(ld, 1);
                const int   pi = __shfl_up(li, 1);
                if (gt) {
                    if (lane == p) { ld = dc; li = ic; }
                    else           { ld = pd; li = pi; }   // shift up by one
                }
                td = __shfl(ld, 16);
                ti = __shfl(li, 16);
                // Safe d2 bound: dist < td (or tie) implies d2 <= td^2*(1+1e-6).
                td2u = td * td * 1.000001f;
            }
        }
    }

    // Neighbors = sorted entries at lanes 1..16 (lane 0 is self / lex-min).
    int nb[KK];
#pragma unroll
    for (int m = 0; m < KK; ++m) nb[m] = __shfl(li, m + 1);

    float* orow = out + (size_t)row * NN;
    const float4 z4 = make_float4(0.f, 0.f, 0.f, 0.f);
#pragma unroll 4
    for (int u = 0; u < NN / 256; ++u) {
        // Wave writes 1 KB contiguous per iteration: fully coalesced.
        *reinterpret_cast<float4*>(orow + u * 256 + lane * 4) = z4;
    }
    // Drain stores so the 1.0 overwrites (same lane, same address) land after.
    asm volatile("s_waitcnt vmcnt(0)" ::: "memory");
#pragma unroll
    for (int m = 0; m < KK; ++m) {
        const int c = nb[m];
        if (((c >> 2) & 63) == lane) orow[c] = 1.0f;  // owner lane rewrites its col
    }
}

extern "C" void kernel_launch(void* const* d_in, const int* in_sizes, int n_in,
                              void* d_out, int out_size, void* d_ws, size_t ws_size,
                              hipStream_t stream) {
    const float* nodes = (const float*)d_in[0];
    float* out = (float*)d_out;
    (void)in_sizes; (void)n_in; (void)out_size; (void)d_ws; (void)ws_size;
    dim3 grid(NN / 4);   // 4 waves per 256-thread block, one row per wave
    dim3 block(256);
    hipLaunchKernelGGL(knn_adj_kernel, grid, block, 0, stream, nodes, out);
}